// Round 2
// baseline (940.759 us; speedup 1.0000x reference)
//
#include <hip/hip_runtime.h>
#include <math.h>

// ---------------------------------------------------------------------------
// StageA GNN: encoder -> CSR build -> L x (gate-proj, fused agg+update+LN) -> head
// R2: replace atomic edge scatter with dst-sorted CSR + wave-per-node
// aggregation fused with the update MLP + LayerNorm (ping-pong h buffers).
// Per-edge record (src, base_w*rho_s*rho_d) is layer-invariant, built once.
// ---------------------------------------------------------------------------

__device__ __forceinline__ float wave_sum64(float v) {
    #pragma unroll
    for (int o = 32; o > 0; o >>= 1) v += __shfl_xor(v, o, 64);
    return v;
}

__global__ __launch_bounds__(256) void rho_kernel(
    const float* __restrict__ rr, float* __restrict__ rho, int N) {
    int i = blockIdx.x * blockDim.x + threadIdx.x;
    if (i < N) rho[i] = 1.0f / (1.0f + __expf(-rr[i]));
}

// h = relu(relu(x@W1+b1)@W2+b2); wave-per-row, W1 in LDS (64KB), W2 via L1.
__global__ __launch_bounds__(256) void enc_kernel(
    const float* __restrict__ x, const float* __restrict__ w1,
    const float* __restrict__ b1, const float* __restrict__ w2,
    const float* __restrict__ b2, float* __restrict__ h, int N, int C) {
    __shared__ float ws1[256 * 64];  // 64 KB
    for (int i = threadIdx.x; i < C * 64; i += blockDim.x) ws1[i] = w1[i];
    __syncthreads();
    const int lane = threadIdx.x & 63;
    const int wid  = blockIdx.x * (blockDim.x >> 6) + (threadIdx.x >> 6);
    const int nw   = gridDim.x * (blockDim.x >> 6);
    const float b1l = b1[lane], b2l = b2[lane];
    for (int r = wid; r < N; r += nw) {
        const float4* xr = (const float4*)(x + (size_t)r * C);
        float acc = 0.f;
        for (int k4 = 0; k4 < C / 4; ++k4) {
            float4 xv = xr[k4];
            int k = k4 * 4;
            acc = fmaf(ws1[(k + 0) * 64 + lane], xv.x, acc);
            acc = fmaf(ws1[(k + 1) * 64 + lane], xv.y, acc);
            acc = fmaf(ws1[(k + 2) * 64 + lane], xv.z, acc);
            acc = fmaf(ws1[(k + 3) * 64 + lane], xv.w, acc);
        }
        float t1 = fmaxf(acc + b1l, 0.f);
        float acc2 = 0.f;
        #pragma unroll
        for (int k = 0; k < 64; ++k) {
            float tv = __shfl(t1, k, 64);
            acc2 = fmaf(w2[k * 64 + lane], tv, acc2);
        }
        h[(size_t)r * 64 + lane] = fmaxf(acc2 + b2l, 0.f);
    }
}

// ---- CSR build (once per call, reused by both layers) ----
__global__ __launch_bounds__(256) void hist_kernel(
    const int* __restrict__ dst, int* __restrict__ cnt, int E) {
    for (int e = blockIdx.x * blockDim.x + threadIdx.x; e < E;
         e += gridDim.x * blockDim.x)
        atomicAdd(&cnt[dst[e]], 1);
}

// single-block exclusive scan: cnt[N] -> row_ptr[N+1]
__global__ __launch_bounds__(1024) void scan_kernel(
    const int* __restrict__ cnt, int* __restrict__ row_ptr, int N) {
    __shared__ int sums[1024];
    const int tid = threadIdx.x;
    const int chunk = (N + 1023) / 1024;
    const int beg = tid * chunk;
    const int end = min(beg + chunk, N);
    int s = 0;
    for (int i = beg; i < end; ++i) s += cnt[i];
    sums[tid] = s;
    __syncthreads();
    for (int off = 1; off < 1024; off <<= 1) {
        int v = (tid >= off) ? sums[tid - off] : 0;
        __syncthreads();
        sums[tid] += v;
        __syncthreads();
    }
    int run = (tid == 0) ? 0 : sums[tid - 1];
    for (int i = beg; i < end; ++i) {
        row_ptr[i] = run;
        run += cnt[i];
    }
    if (tid == 1023) row_ptr[N] = sums[1023];
}

// fill sorted records: (src, base_w*rho_s*rho_d), grouped by dst
__global__ __launch_bounds__(256) void scatter_kernel(
    const int* __restrict__ src, const int* __restrict__ dst,
    const float* __restrict__ base_w, const float* __restrict__ rho,
    const int* __restrict__ row_ptr, int* __restrict__ fill,
    int2* __restrict__ recs, int E) {
    for (int e = blockIdx.x * blockDim.x + threadIdx.x; e < E;
         e += gridDim.x * blockDim.x) {
        int s = src[e], d = dst[e];
        int pos = row_ptr[d] + atomicAdd(&fill[d], 1);
        float c = base_w[e] * rho[s] * rho[d];
        recs[pos] = make_int2(s, __float_as_int(c));
    }
}

// a = h@gw1[0:64] + gb1 ; bb = h@gw1[64:128]; also pack ah = [a | h] per node
__global__ __launch_bounds__(256) void gateproj_kernel(
    const float* __restrict__ h, const float* __restrict__ gw1,
    const float* __restrict__ gb1, float* __restrict__ ah,
    float* __restrict__ bb, int N) {
    __shared__ float ws[128 * 64];  // 32 KB
    for (int i = threadIdx.x; i < 128 * 64; i += blockDim.x) ws[i] = gw1[i];
    __syncthreads();
    const int lane = threadIdx.x & 63;
    const int wid  = blockIdx.x * (blockDim.x >> 6) + (threadIdx.x >> 6);
    const int nw   = gridDim.x * (blockDim.x >> 6);
    const float gb = gb1[lane];
    for (int r = wid; r < N; r += nw) {
        float hv = h[(size_t)r * 64 + lane];
        float aacc = 0.f, bacc = 0.f;
        #pragma unroll
        for (int k = 0; k < 64; ++k) {
            float tv = __shfl(hv, k, 64);
            aacc = fmaf(ws[k * 64 + lane], tv, aacc);
            bacc = fmaf(ws[(64 + k) * 64 + lane], tv, bacc);
        }
        ah[(size_t)r * 128 + lane]      = aacc + gb;   // a
        ah[(size_t)r * 128 + 64 + lane] = hv;          // h copy (gather locality)
        bb[(size_t)r * 64 + lane]       = bacc;
    }
}

// wave-per-node: loop dst-grouped edges, gate+weighted sum in registers,
// then fused update MLP + LayerNorm. Reads h via ah (old), writes h_out (new).
__global__ __launch_bounds__(256) void agg_update_kernel(
    const int* __restrict__ row_ptr, const int2* __restrict__ recs,
    const float* __restrict__ ah, const float* __restrict__ bb,
    const float* __restrict__ h_in, const float* __restrict__ gw2,
    const float* __restrict__ gb2,
    const float* __restrict__ w1, const float* __restrict__ b1,
    const float* __restrict__ w2, const float* __restrict__ b2,
    const float* __restrict__ lng, const float* __restrict__ lnb,
    float* __restrict__ h_out, int N) {
    __shared__ float ws1[64 * 64], ws2[64 * 64];  // 16 + 16 KB
    for (int i = threadIdx.x; i < 4096; i += blockDim.x) {
        ws1[i] = w1[i];
        ws2[i] = w2[i];
    }
    __syncthreads();
    const int lane = threadIdx.x & 63;
    const int wid  = blockIdx.x * (blockDim.x >> 6) + (threadIdx.x >> 6);
    const int nw   = gridDim.x * (blockDim.x >> 6);
    const float gv = gw2[lane];
    const float gb = gb2[0];
    const float b1l = b1[lane], b2l = b2[lane];
    const float gl = lng[lane], bl = lnb[lane];
    for (int n = wid; n < N; n += nw) {
        const int beg = row_ptr[n], end = row_ptr[n + 1];
        const float bv = bb[(size_t)n * 64 + lane];
        float macc = 0.f, dacc = 0.f;
        int i = beg;
        for (; i + 2 <= end; i += 2) {               // 2-way unroll for ILP
            int2 r0 = recs[i], r1 = recs[i + 1];
            size_t o0 = (size_t)r0.x * 128 + lane;
            size_t o1 = (size_t)r1.x * 128 + lane;
            float av0 = ah[o0],      av1 = ah[o1];
            float hv0 = ah[o0 + 64], hv1 = ah[o1 + 64];
            float z0 = fmaxf(av0 + bv, 0.f) * gv;
            float z1 = fmaxf(av1 + bv, 0.f) * gv;
            #pragma unroll
            for (int o = 32; o > 0; o >>= 1) {
                z0 += __shfl_xor(z0, o, 64);
                z1 += __shfl_xor(z1, o, 64);
            }
            float c0 = __int_as_float(r0.y), c1 = __int_as_float(r1.y);
            float w0  = c0 / (1.f + __expf(-(z0 + gb)));
            float w1v = c1 / (1.f + __expf(-(z1 + gb)));
            macc = fmaf(w0, hv0, macc);
            macc = fmaf(w1v, hv1, macc);
            dacc += w0 + w1v;
        }
        if (i < end) {
            int2 r0 = recs[i];
            size_t o0 = (size_t)r0.x * 128 + lane;
            float av0 = ah[o0], hv0 = ah[o0 + 64];
            float z0 = fmaxf(av0 + bv, 0.f) * gv;
            z0 = wave_sum64(z0);
            float w0 = __int_as_float(r0.y) / (1.f + __expf(-(z0 + gb)));
            macc = fmaf(w0, hv0, macc);
            dacc += w0;
        }
        // ---- fused update MLP + LayerNorm ----
        float neigh = macc / (dacc + 1e-8f);
        float acc = 0.f;
        #pragma unroll
        for (int k = 0; k < 64; ++k) {
            float tv = __shfl(neigh, k, 64);
            acc = fmaf(ws1[k * 64 + lane], tv, acc);
        }
        float t = fmaxf(acc + b1l, 0.f);
        float acc2 = 0.f;
        #pragma unroll
        for (int k = 0; k < 64; ++k) {
            float tv = __shfl(t, k, 64);
            acc2 = fmaf(ws2[k * 64 + lane], tv, acc2);
        }
        float pre = h_in[(size_t)n * 64 + lane] + acc2 + b2l;
        float s1 = wave_sum64(pre);
        float s2 = wave_sum64(pre * pre);
        float mean = s1 * (1.0f / 64.0f);
        float var  = s2 * (1.0f / 64.0f) - mean * mean;
        float hn = (pre - mean) * rsqrtf(var + 1e-5f) * gl + bl;
        h_out[(size_t)n * 64 + lane] = hn;
    }
}

// U = softplus(h @ toU_w + toU_b), K=32
__global__ __launch_bounds__(256) void out_kernel(
    const float* __restrict__ h, const float* __restrict__ tw,
    const float* __restrict__ tb, float* __restrict__ U, int N) {
    int gid = blockIdx.x * blockDim.x + threadIdx.x;
    int n = gid >> 5;
    int k = gid & 31;
    if (n >= N) return;
    float acc = tb[k];
    const float* hr = h + (size_t)n * 64;
    #pragma unroll 8
    for (int j = 0; j < 64; ++j) acc = fmaf(hr[j], tw[j * 32 + k], acc);
    float sp = acc > 0.f ? acc + log1pf(__expf(-acc)) : log1pf(__expf(acc));
    U[(size_t)n * 32 + k] = sp;
}

extern "C" void kernel_launch(void* const* d_in, const int* in_sizes, int n_in,
                              void* d_out, int out_size, void* d_ws, size_t ws_size,
                              hipStream_t stream) {
    const float* x       = (const float*)d_in[0];
    const int*   src     = (const int*)d_in[1];
    const int*   dst     = (const int*)d_in[2];
    const float* base_w  = (const float*)d_in[3];
    const float* enc_w1  = (const float*)d_in[4];
    const float* enc_b1  = (const float*)d_in[5];
    const float* enc_w2  = (const float*)d_in[6];
    const float* enc_b2  = (const float*)d_in[7];
    const float* gate_w1 = (const float*)d_in[8];
    const float* gate_b1 = (const float*)d_in[9];
    const float* gate_w2 = (const float*)d_in[10];
    const float* gate_b2 = (const float*)d_in[11];
    const float* upd_w1  = (const float*)d_in[12];
    const float* upd_b1  = (const float*)d_in[13];
    const float* upd_w2  = (const float*)d_in[14];
    const float* upd_b2  = (const float*)d_in[15];
    const float* ln_g    = (const float*)d_in[16];
    const float* ln_b    = (const float*)d_in[17];
    const float* rho_raw = (const float*)d_in[18];
    const float* toU_w   = (const float*)d_in[19];
    const float* toU_b   = (const float*)d_in[20];

    const int N = in_sizes[18];          // 50000
    const int C = in_sizes[0] / N;       // 256
    const int E = in_sizes[1];           // 800000
    const int L = 2;

    // workspace layout (floats), sections kept 8B-aligned
    float* ws  = (float*)d_ws;
    size_t off = 0;
    float* rho = ws + off; off += N;                    // N even
    float* h0  = ws + off; off += (size_t)N * 64;
    float* h1  = ws + off; off += (size_t)N * 64;
    float* ah  = ws + off; off += (size_t)N * 128;      // [a | h] interleaved
    float* bb  = ws + off; off += (size_t)N * 64;
    int* row_ptr = (int*)(ws + off); off += (size_t)N + 2;  // N+1, pad to even
    int* cnt     = (int*)(ws + off); off += N;              // reused as fill
    int2* recs   = (int2*)(ws + off); off += (size_t)E * 2;

    rho_kernel<<<(N + 255) / 256, 256, 0, stream>>>(rho_raw, rho, N);
    enc_kernel<<<512, 256, 0, stream>>>(x, enc_w1, enc_b1, enc_w2, enc_b2, h0, N, C);

    // CSR build (dst-sorted edge records)
    hipMemsetAsync(cnt, 0, (size_t)N * sizeof(int), stream);
    hist_kernel<<<(E + 255) / 256, 256, 0, stream>>>(dst, cnt, E);
    scan_kernel<<<1, 1024, 0, stream>>>(cnt, row_ptr, N);
    hipMemsetAsync(cnt, 0, (size_t)N * sizeof(int), stream);
    scatter_kernel<<<(E + 255) / 256, 256, 0, stream>>>(src, dst, base_w, rho,
                                                        row_ptr, cnt, recs, E);

    float* h_cur = h0;
    float* h_nxt = h1;
    for (int l = 0; l < L; ++l) {
        gateproj_kernel<<<1024, 256, 0, stream>>>(h_cur, gate_w1, gate_b1, ah, bb, N);
        agg_update_kernel<<<2048, 256, 0, stream>>>(
            row_ptr, recs, ah, bb, h_cur, gate_w2, gate_b2,
            upd_w1 + (size_t)l * 4096, upd_b1 + l * 64,
            upd_w2 + (size_t)l * 4096, upd_b2 + l * 64,
            ln_g + l * 64, ln_b + l * 64, h_nxt, N);
        float* tmp = h_cur; h_cur = h_nxt; h_nxt = tmp;
    }

    out_kernel<<<((N * 32) + 255) / 256, 256, 0, stream>>>(h_cur, toU_w, toU_b,
                                                           (float*)d_out, N);
}

// Round 3
// 801.796 us; speedup vs baseline: 1.1733x; 1.1733x over previous
//
#include <hip/hip_runtime.h>
#include <math.h>

// ---------------------------------------------------------------------------
// StageA GNN: encoder -> CSR build -> L x (gate-proj, gate, agg+update+LN) -> head
// R3: split edge phase into (a) gate_kernel — 16 lanes/edge, float4 slices,
// 4-step reduce, no LDS, full occupancy; (b) agg_update — pure gather+fma
// inner loop (no cross-lane ops), 4-way unroll. Gathers read h directly.
// ---------------------------------------------------------------------------

__device__ __forceinline__ float wave_sum64(float v) {
    #pragma unroll
    for (int o = 32; o > 0; o >>= 1) v += __shfl_xor(v, o, 64);
    return v;
}

__global__ __launch_bounds__(256) void rho_kernel(
    const float* __restrict__ rr, float* __restrict__ rho, int N) {
    int i = blockIdx.x * blockDim.x + threadIdx.x;
    if (i < N) rho[i] = 1.0f / (1.0f + __expf(-rr[i]));
}

// h = relu(relu(x@W1+b1)@W2+b2); wave-per-row, W1 in LDS (64KB), W2 via L1.
__global__ __launch_bounds__(256) void enc_kernel(
    const float* __restrict__ x, const float* __restrict__ w1,
    const float* __restrict__ b1, const float* __restrict__ w2,
    const float* __restrict__ b2, float* __restrict__ h, int N, int C) {
    __shared__ float ws1[256 * 64];  // 64 KB
    for (int i = threadIdx.x; i < C * 64; i += blockDim.x) ws1[i] = w1[i];
    __syncthreads();
    const int lane = threadIdx.x & 63;
    const int wid  = blockIdx.x * (blockDim.x >> 6) + (threadIdx.x >> 6);
    const int nw   = gridDim.x * (blockDim.x >> 6);
    const float b1l = b1[lane], b2l = b2[lane];
    for (int r = wid; r < N; r += nw) {
        const float4* xr = (const float4*)(x + (size_t)r * C);
        float acc = 0.f;
        for (int k4 = 0; k4 < C / 4; ++k4) {
            float4 xv = xr[k4];
            int k = k4 * 4;
            acc = fmaf(ws1[(k + 0) * 64 + lane], xv.x, acc);
            acc = fmaf(ws1[(k + 1) * 64 + lane], xv.y, acc);
            acc = fmaf(ws1[(k + 2) * 64 + lane], xv.z, acc);
            acc = fmaf(ws1[(k + 3) * 64 + lane], xv.w, acc);
        }
        float t1 = fmaxf(acc + b1l, 0.f);
        float acc2 = 0.f;
        #pragma unroll
        for (int k = 0; k < 64; ++k) {
            float tv = __shfl(t1, k, 64);
            acc2 = fmaf(w2[k * 64 + lane], tv, acc2);
        }
        h[(size_t)r * 64 + lane] = fmaxf(acc2 + b2l, 0.f);
    }
}

// ---- CSR build (once per call, reused by both layers) ----
__global__ __launch_bounds__(256) void hist_kernel(
    const int* __restrict__ dst, int* __restrict__ cnt, int E) {
    for (int e = blockIdx.x * blockDim.x + threadIdx.x; e < E;
         e += gridDim.x * blockDim.x)
        atomicAdd(&cnt[dst[e]], 1);
}

// single-block exclusive scan: cnt[N] -> row_ptr[N+1]
__global__ __launch_bounds__(1024) void scan_kernel(
    const int* __restrict__ cnt, int* __restrict__ row_ptr, int N) {
    __shared__ int sums[1024];
    const int tid = threadIdx.x;
    const int chunk = (N + 1023) / 1024;
    const int beg = tid * chunk;
    const int end = min(beg + chunk, N);
    int s = 0;
    for (int i = beg; i < end; ++i) s += cnt[i];
    sums[tid] = s;
    __syncthreads();
    for (int off = 1; off < 1024; off <<= 1) {
        int v = (tid >= off) ? sums[tid - off] : 0;
        __syncthreads();
        sums[tid] += v;
        __syncthreads();
    }
    int run = (tid == 0) ? 0 : sums[tid - 1];
    for (int i = beg; i < end; ++i) {
        row_ptr[i] = run;
        run += cnt[i];
    }
    if (tid == 1023) row_ptr[N] = sums[1023];
}

// fill dst-grouped records: (src, dst, base_w*rho_s*rho_d, pad)
__global__ __launch_bounds__(256) void scatter_kernel(
    const int* __restrict__ src, const int* __restrict__ dst,
    const float* __restrict__ base_w, const float* __restrict__ rho,
    const int* __restrict__ row_ptr, int* __restrict__ fill,
    int4* __restrict__ recs, int E) {
    for (int e = blockIdx.x * blockDim.x + threadIdx.x; e < E;
         e += gridDim.x * blockDim.x) {
        int s = src[e], d = dst[e];
        int pos = row_ptr[d] + atomicAdd(&fill[d], 1);
        float c = base_w[e] * rho[s] * rho[d];
        recs[pos] = make_int4(s, d, __float_as_int(c), 0);
    }
}

// a = h@gw1[0:64] + gb1 ; bb = h@gw1[64:128]
__global__ __launch_bounds__(256) void gateproj_kernel(
    const float* __restrict__ h, const float* __restrict__ gw1,
    const float* __restrict__ gb1, float* __restrict__ a,
    float* __restrict__ bb, int N) {
    __shared__ float ws[128 * 64];  // 32 KB
    for (int i = threadIdx.x; i < 128 * 64; i += blockDim.x) ws[i] = gw1[i];
    __syncthreads();
    const int lane = threadIdx.x & 63;
    const int wid  = blockIdx.x * (blockDim.x >> 6) + (threadIdx.x >> 6);
    const int nw   = gridDim.x * (blockDim.x >> 6);
    const float gb = gb1[lane];
    for (int r = wid; r < N; r += nw) {
        float hv = h[(size_t)r * 64 + lane];
        float aacc = 0.f, bacc = 0.f;
        #pragma unroll
        for (int k = 0; k < 64; ++k) {
            float tv = __shfl(hv, k, 64);
            aacc = fmaf(ws[k * 64 + lane], tv, aacc);
            bacc = fmaf(ws[(64 + k) * 64 + lane], tv, bacc);
        }
        a[(size_t)r * 64 + lane]  = aacc + gb;
        bb[(size_t)r * 64 + lane] = bacc;
    }
}

// 16 lanes per edge: z = relu(a[s]+bb[d]) dot gw2 (float4/lane, 4-step reduce)
// w = c * sigmoid(z + gb2);  sw[e] = (s, w).  No LDS -> full occupancy.
__global__ __launch_bounds__(256) void gate_kernel(
    const int4* __restrict__ recs, const float* __restrict__ a,
    const float* __restrict__ bb, const float* __restrict__ gw2,
    const float* __restrict__ gb2, int2* __restrict__ sw, int E) {
    const int lane = threadIdx.x & 63;
    const int sub  = lane & 15;                       // feature slice id
    const float4 gv = ((const float4*)gw2)[sub];
    const float gb = gb2[0];
    int grp  = (blockIdx.x * blockDim.x + threadIdx.x) >> 4;
    const int ngrp = (gridDim.x * blockDim.x) >> 4;
    for (int e = grp; e < E; e += ngrp) {
        int4 r = recs[e];                             // broadcast within group
        float4 av = ((const float4*)(a  + (size_t)r.x * 64))[sub];
        float4 bv = ((const float4*)(bb + (size_t)r.y * 64))[sub];
        float t = fmaxf(av.x + bv.x, 0.f) * gv.x
                + fmaxf(av.y + bv.y, 0.f) * gv.y
                + fmaxf(av.z + bv.z, 0.f) * gv.z
                + fmaxf(av.w + bv.w, 0.f) * gv.w;
        #pragma unroll
        for (int o = 8; o > 0; o >>= 1) t += __shfl_xor(t, o, 64);
        float w = __int_as_float(r.z) / (1.f + __expf(-(t + gb)));
        if (sub == 0) sw[e] = make_int2(r.x, __float_as_int(w));
    }
}

// wave-per-node: pure gather+fma aggregation (no cross-lane in the loop),
// then fused update MLP + LayerNorm. Reads h_in, writes h_out.
__global__ __launch_bounds__(256) void agg_update_kernel(
    const int* __restrict__ row_ptr, const int2* __restrict__ sw,
    const float* __restrict__ h_in,
    const float* __restrict__ w1, const float* __restrict__ b1,
    const float* __restrict__ w2, const float* __restrict__ b2,
    const float* __restrict__ lng, const float* __restrict__ lnb,
    float* __restrict__ h_out, int N) {
    __shared__ float ws1[64 * 64], ws2[64 * 64];  // 16 + 16 KB
    for (int i = threadIdx.x; i < 4096; i += blockDim.x) {
        ws1[i] = w1[i];
        ws2[i] = w2[i];
    }
    __syncthreads();
    const int lane = threadIdx.x & 63;
    const int wid  = blockIdx.x * (blockDim.x >> 6) + (threadIdx.x >> 6);
    const int nw   = gridDim.x * (blockDim.x >> 6);
    const float b1l = b1[lane], b2l = b2[lane];
    const float gl = lng[lane], bl = lnb[lane];
    for (int n = wid; n < N; n += nw) {
        const int beg = row_ptr[n], end = row_ptr[n + 1];
        float macc = 0.f, dacc = 0.f;
        int i = beg;
        for (; i + 4 <= end; i += 4) {
            int2 r0 = sw[i], r1 = sw[i + 1], r2 = sw[i + 2], r3 = sw[i + 3];
            float hv0 = h_in[(size_t)r0.x * 64 + lane];
            float hv1 = h_in[(size_t)r1.x * 64 + lane];
            float hv2 = h_in[(size_t)r2.x * 64 + lane];
            float hv3 = h_in[(size_t)r3.x * 64 + lane];
            float w0 = __int_as_float(r0.y), w1v = __int_as_float(r1.y);
            float w2v = __int_as_float(r2.y), w3v = __int_as_float(r3.y);
            macc = fmaf(w0, hv0, macc);
            macc = fmaf(w1v, hv1, macc);
            macc = fmaf(w2v, hv2, macc);
            macc = fmaf(w3v, hv3, macc);
            dacc += (w0 + w1v) + (w2v + w3v);
        }
        for (; i < end; ++i) {
            int2 r0 = sw[i];
            float hv0 = h_in[(size_t)r0.x * 64 + lane];
            float w0 = __int_as_float(r0.y);
            macc = fmaf(w0, hv0, macc);
            dacc += w0;
        }
        // ---- fused update MLP + LayerNorm ----
        float neigh = macc / (dacc + 1e-8f);
        float acc = 0.f;
        #pragma unroll
        for (int k = 0; k < 64; ++k) {
            float tv = __shfl(neigh, k, 64);
            acc = fmaf(ws1[k * 64 + lane], tv, acc);
        }
        float t = fmaxf(acc + b1l, 0.f);
        float acc2 = 0.f;
        #pragma unroll
        for (int k = 0; k < 64; ++k) {
            float tv = __shfl(t, k, 64);
            acc2 = fmaf(ws2[k * 64 + lane], tv, acc2);
        }
        float pre = h_in[(size_t)n * 64 + lane] + acc2 + b2l;
        float s1 = wave_sum64(pre);
        float s2 = wave_sum64(pre * pre);
        float mean = s1 * (1.0f / 64.0f);
        float var  = s2 * (1.0f / 64.0f) - mean * mean;
        float hn = (pre - mean) * rsqrtf(var + 1e-5f) * gl + bl;
        h_out[(size_t)n * 64 + lane] = hn;
    }
}

// U = softplus(h @ toU_w + toU_b), K=32
__global__ __launch_bounds__(256) void out_kernel(
    const float* __restrict__ h, const float* __restrict__ tw,
    const float* __restrict__ tb, float* __restrict__ U, int N) {
    int gid = blockIdx.x * blockDim.x + threadIdx.x;
    int n = gid >> 5;
    int k = gid & 31;
    if (n >= N) return;
    float acc = tb[k];
    const float* hr = h + (size_t)n * 64;
    #pragma unroll 8
    for (int j = 0; j < 64; ++j) acc = fmaf(hr[j], tw[j * 32 + k], acc);
    float sp = acc > 0.f ? acc + log1pf(__expf(-acc)) : log1pf(__expf(acc));
    U[(size_t)n * 32 + k] = sp;
}

extern "C" void kernel_launch(void* const* d_in, const int* in_sizes, int n_in,
                              void* d_out, int out_size, void* d_ws, size_t ws_size,
                              hipStream_t stream) {
    const float* x       = (const float*)d_in[0];
    const int*   src     = (const int*)d_in[1];
    const int*   dst     = (const int*)d_in[2];
    const float* base_w  = (const float*)d_in[3];
    const float* enc_w1  = (const float*)d_in[4];
    const float* enc_b1  = (const float*)d_in[5];
    const float* enc_w2  = (const float*)d_in[6];
    const float* enc_b2  = (const float*)d_in[7];
    const float* gate_w1 = (const float*)d_in[8];
    const float* gate_b1 = (const float*)d_in[9];
    const float* gate_w2 = (const float*)d_in[10];
    const float* gate_b2 = (const float*)d_in[11];
    const float* upd_w1  = (const float*)d_in[12];
    const float* upd_b1  = (const float*)d_in[13];
    const float* upd_w2  = (const float*)d_in[14];
    const float* upd_b2  = (const float*)d_in[15];
    const float* ln_g    = (const float*)d_in[16];
    const float* ln_b    = (const float*)d_in[17];
    const float* rho_raw = (const float*)d_in[18];
    const float* toU_w   = (const float*)d_in[19];
    const float* toU_b   = (const float*)d_in[20];

    const int N = in_sizes[18];          // 50000
    const int C = in_sizes[0] / N;       // 256
    const int E = in_sizes[1];           // 800000
    const int L = 2;

    // workspace layout (floats), sections padded to 16B alignment
    float* ws  = (float*)d_ws;
    size_t off = 0;
    float* rho = ws + off; off += (size_t)((N + 3) & ~3);
    float* h0  = ws + off; off += (size_t)N * 64;
    float* h1  = ws + off; off += (size_t)N * 64;
    float* a   = ws + off; off += (size_t)N * 64;
    float* bb  = ws + off; off += (size_t)N * 64;
    int* row_ptr = (int*)(ws + off); off += (size_t)((N + 1 + 3) & ~3);
    int* cnt     = (int*)(ws + off); off += (size_t)((N + 3) & ~3);
    int4* recs   = (int4*)(ws + off); off += (size_t)E * 4;   // (s,d,c,0)
    int2* sw     = (int2*)(ws + off); off += (size_t)E * 2;   // (s,w)

    rho_kernel<<<(N + 255) / 256, 256, 0, stream>>>(rho_raw, rho, N);
    enc_kernel<<<512, 256, 0, stream>>>(x, enc_w1, enc_b1, enc_w2, enc_b2, h0, N, C);

    // CSR build (dst-sorted edge records)
    hipMemsetAsync(cnt, 0, (size_t)N * sizeof(int), stream);
    hist_kernel<<<(E + 255) / 256, 256, 0, stream>>>(dst, cnt, E);
    scan_kernel<<<1, 1024, 0, stream>>>(cnt, row_ptr, N);
    hipMemsetAsync(cnt, 0, (size_t)N * sizeof(int), stream);
    scatter_kernel<<<(E + 255) / 256, 256, 0, stream>>>(src, dst, base_w, rho,
                                                        row_ptr, cnt, recs, E);

    float* h_cur = h0;
    float* h_nxt = h1;
    for (int l = 0; l < L; ++l) {
        gateproj_kernel<<<1024, 256, 0, stream>>>(h_cur, gate_w1, gate_b1, a, bb, N);
        gate_kernel<<<4096, 256, 0, stream>>>(recs, a, bb, gate_w2, gate_b2, sw, E);
        agg_update_kernel<<<2048, 256, 0, stream>>>(
            row_ptr, sw, h_cur,
            upd_w1 + (size_t)l * 4096, upd_b1 + l * 64,
            upd_w2 + (size_t)l * 4096, upd_b2 + l * 64,
            ln_g + l * 64, ln_b + l * 64, h_nxt, N);
        float* tmp = h_cur; h_cur = h_nxt; h_nxt = tmp;
    }

    out_kernel<<<((N * 32) + 255) / 256, 256, 0, stream>>>(h_cur, toU_w, toU_b,
                                                           (float*)d_out, N);
}

// Round 4
// 797.409 us; speedup vs baseline: 1.1798x; 1.0055x over previous
//
#include <hip/hip_runtime.h>
#include <math.h>

// ---------------------------------------------------------------------------
// StageA GNN: encoder -> CSR build -> L x (gate-proj, gate, agg+update+LN) -> head
// R4: (a) enc_kernel processes 4 rows/wave (shared LDS reads, 4 indep FMA
// chains); (b) gathered operands (h rows, gate 'a' projection) stored packed
// bf16 -> halves random-gather traffic in gate/agg (the dominant cost);
// all accumulation / GEMVs / residual / LN remain fp32.
// ---------------------------------------------------------------------------

typedef unsigned short ushort_t;

__device__ __forceinline__ float bf2f(ushort_t u) {
    return __uint_as_float(((unsigned int)u) << 16);
}
__device__ __forceinline__ ushort_t f2bf(float f) {
    unsigned int x = __float_as_uint(f);
    unsigned int lsb = (x >> 16) & 1u;
    x += 0x7fffu + lsb;                 // round-to-nearest-even
    return (ushort_t)(x >> 16);
}

__device__ __forceinline__ float wave_sum64(float v) {
    #pragma unroll
    for (int o = 32; o > 0; o >>= 1) v += __shfl_xor(v, o, 64);
    return v;
}

// h = relu(relu(x@W1+b1)@W2+b2); 4 rows per wave, W1 in LDS (64KB).
__global__ __launch_bounds__(256) void enc_kernel(
    const float* __restrict__ x, const float* __restrict__ w1,
    const float* __restrict__ b1, const float* __restrict__ w2,
    const float* __restrict__ b2, float* __restrict__ h,
    ushort_t* __restrict__ hb, int N, int C) {
    __shared__ float ws1[256 * 64];  // 64 KB
    for (int i = threadIdx.x; i < C * 64; i += blockDim.x) ws1[i] = w1[i];
    __syncthreads();
    const int lane = threadIdx.x & 63;
    const int wid  = blockIdx.x * (blockDim.x >> 6) + (threadIdx.x >> 6);
    const int nw   = gridDim.x * (blockDim.x >> 6);
    const float b1l = b1[lane], b2l = b2[lane];
    const int nquad = (N + 3) >> 2;
    for (int q = wid; q < nquad; q += nw) {
        const int r0 = q * 4;
        if (r0 + 3 < N) {
            const float4* x0 = (const float4*)(x + (size_t)r0 * C);
            const float4* x1 = x0 + (C >> 2);
            const float4* x2 = x1 + (C >> 2);
            const float4* x3 = x2 + (C >> 2);
            float a0 = 0.f, a1 = 0.f, a2 = 0.f, a3 = 0.f;
            for (int k4 = 0; k4 < C / 4; ++k4) {
                float4 v0 = x0[k4], v1 = x1[k4], v2 = x2[k4], v3 = x3[k4];
                const float* wp = &ws1[k4 * 4 * 64 + lane];
                float wa = wp[0], wb = wp[64], wc = wp[128], wd = wp[192];
                a0 = fmaf(wa, v0.x, a0); a0 = fmaf(wb, v0.y, a0);
                a0 = fmaf(wc, v0.z, a0); a0 = fmaf(wd, v0.w, a0);
                a1 = fmaf(wa, v1.x, a1); a1 = fmaf(wb, v1.y, a1);
                a1 = fmaf(wc, v1.z, a1); a1 = fmaf(wd, v1.w, a1);
                a2 = fmaf(wa, v2.x, a2); a2 = fmaf(wb, v2.y, a2);
                a2 = fmaf(wc, v2.z, a2); a2 = fmaf(wd, v2.w, a2);
                a3 = fmaf(wa, v3.x, a3); a3 = fmaf(wb, v3.y, a3);
                a3 = fmaf(wc, v3.z, a3); a3 = fmaf(wd, v3.w, a3);
            }
            float t0 = fmaxf(a0 + b1l, 0.f), t1 = fmaxf(a1 + b1l, 0.f);
            float t2 = fmaxf(a2 + b1l, 0.f), t3 = fmaxf(a3 + b1l, 0.f);
            float c0 = 0.f, c1 = 0.f, c2 = 0.f, c3 = 0.f;
            #pragma unroll
            for (int k = 0; k < 64; ++k) {
                float wv = w2[k * 64 + lane];
                c0 = fmaf(wv, __shfl(t0, k, 64), c0);
                c1 = fmaf(wv, __shfl(t1, k, 64), c1);
                c2 = fmaf(wv, __shfl(t2, k, 64), c2);
                c3 = fmaf(wv, __shfl(t3, k, 64), c3);
            }
            float h0v = fmaxf(c0 + b2l, 0.f), h1v = fmaxf(c1 + b2l, 0.f);
            float h2v = fmaxf(c2 + b2l, 0.f), h3v = fmaxf(c3 + b2l, 0.f);
            h[(size_t)(r0 + 0) * 64 + lane] = h0v;
            h[(size_t)(r0 + 1) * 64 + lane] = h1v;
            h[(size_t)(r0 + 2) * 64 + lane] = h2v;
            h[(size_t)(r0 + 3) * 64 + lane] = h3v;
            hb[(size_t)(r0 + 0) * 64 + lane] = f2bf(h0v);
            hb[(size_t)(r0 + 1) * 64 + lane] = f2bf(h1v);
            hb[(size_t)(r0 + 2) * 64 + lane] = f2bf(h2v);
            hb[(size_t)(r0 + 3) * 64 + lane] = f2bf(h3v);
        } else {
            for (int r = r0; r < N; ++r) {
                const float4* xr = (const float4*)(x + (size_t)r * C);
                float acc = 0.f;
                for (int k4 = 0; k4 < C / 4; ++k4) {
                    float4 xv = xr[k4];
                    int k = k4 * 4;
                    acc = fmaf(ws1[(k + 0) * 64 + lane], xv.x, acc);
                    acc = fmaf(ws1[(k + 1) * 64 + lane], xv.y, acc);
                    acc = fmaf(ws1[(k + 2) * 64 + lane], xv.z, acc);
                    acc = fmaf(ws1[(k + 3) * 64 + lane], xv.w, acc);
                }
                float t = fmaxf(acc + b1l, 0.f);
                float acc2 = 0.f;
                #pragma unroll
                for (int k = 0; k < 64; ++k)
                    acc2 = fmaf(w2[k * 64 + lane], __shfl(t, k, 64), acc2);
                float hv = fmaxf(acc2 + b2l, 0.f);
                h[(size_t)r * 64 + lane] = hv;
                hb[(size_t)r * 64 + lane] = f2bf(hv);
            }
        }
    }
}

// ---- CSR build (once per call, reused by both layers) ----
__global__ __launch_bounds__(256) void hist_kernel(
    const int* __restrict__ dst, int* __restrict__ cnt, int E) {
    for (int e = blockIdx.x * blockDim.x + threadIdx.x; e < E;
         e += gridDim.x * blockDim.x)
        atomicAdd(&cnt[dst[e]], 1);
}

// single-block exclusive scan: cnt[N] -> row_ptr[N+1]
__global__ __launch_bounds__(1024) void scan_kernel(
    const int* __restrict__ cnt, int* __restrict__ row_ptr, int N) {
    __shared__ int sums[1024];
    const int tid = threadIdx.x;
    const int chunk = (N + 1023) / 1024;
    const int beg = tid * chunk;
    const int end = min(beg + chunk, N);
    int s = 0;
    for (int i = beg; i < end; ++i) s += cnt[i];
    sums[tid] = s;
    __syncthreads();
    for (int off = 1; off < 1024; off <<= 1) {
        int v = (tid >= off) ? sums[tid - off] : 0;
        __syncthreads();
        sums[tid] += v;
        __syncthreads();
    }
    int run = (tid == 0) ? 0 : sums[tid - 1];
    for (int i = beg; i < end; ++i) {
        row_ptr[i] = run;
        run += cnt[i];
    }
    if (tid == 1023) row_ptr[N] = sums[1023];
}

// fill dst-grouped records: (src, dst, base_w*sig(rr_s)*sig(rr_d), pad)
__global__ __launch_bounds__(256) void scatter_kernel(
    const int* __restrict__ src, const int* __restrict__ dst,
    const float* __restrict__ base_w, const float* __restrict__ rr,
    const int* __restrict__ row_ptr, int* __restrict__ fill,
    int4* __restrict__ recs, int E) {
    for (int e = blockIdx.x * blockDim.x + threadIdx.x; e < E;
         e += gridDim.x * blockDim.x) {
        int s = src[e], d = dst[e];
        int pos = row_ptr[d] + atomicAdd(&fill[d], 1);
        float rs = 1.f / (1.f + __expf(-rr[s]));
        float rd = 1.f / (1.f + __expf(-rr[d]));
        float c = base_w[e] * rs * rd;
        recs[pos] = make_int4(s, d, __float_as_int(c), 0);
    }
}

// a(bf16) = h@gw1[0:64] + gb1 ; bb(f32) = h@gw1[64:128]
__global__ __launch_bounds__(256) void gateproj_kernel(
    const float* __restrict__ h, const float* __restrict__ gw1,
    const float* __restrict__ gb1, ushort_t* __restrict__ ab,
    float* __restrict__ bb, int N) {
    __shared__ float ws[128 * 64];  // 32 KB
    for (int i = threadIdx.x; i < 128 * 64; i += blockDim.x) ws[i] = gw1[i];
    __syncthreads();
    const int lane = threadIdx.x & 63;
    const int wid  = blockIdx.x * (blockDim.x >> 6) + (threadIdx.x >> 6);
    const int nw   = gridDim.x * (blockDim.x >> 6);
    const float gb = gb1[lane];
    for (int r = wid; r < N; r += nw) {
        float hv = h[(size_t)r * 64 + lane];
        float aacc = 0.f, bacc = 0.f;
        #pragma unroll
        for (int k = 0; k < 64; ++k) {
            float tv = __shfl(hv, k, 64);
            aacc = fmaf(ws[k * 64 + lane], tv, aacc);
            bacc = fmaf(ws[(64 + k) * 64 + lane], tv, bacc);
        }
        ab[(size_t)r * 64 + lane] = f2bf(aacc + gb);
        bb[(size_t)r * 64 + lane] = bacc;
    }
}

// 16 lanes per edge: z = relu(a[s]+bb[d]) dot gw2 (4 elems/lane, 4-step reduce)
// w = c * sigmoid(z + gb2);  sw[e] = (s, w).  a gathered as bf16 (8B/lane).
__global__ __launch_bounds__(256) void gate_kernel(
    const int4* __restrict__ recs, const ushort_t* __restrict__ ab,
    const float* __restrict__ bb, const float* __restrict__ gw2,
    const float* __restrict__ gb2, int2* __restrict__ sw, int E) {
    const int lane = threadIdx.x & 63;
    const int sub  = lane & 15;                       // feature slice id
    const float4 gv = ((const float4*)gw2)[sub];
    const float gb = gb2[0];
    int grp  = (blockIdx.x * blockDim.x + threadIdx.x) >> 4;
    const int ngrp = (gridDim.x * blockDim.x) >> 4;
    for (int e = grp; e < E; e += ngrp) {
        int4 r = recs[e];                             // broadcast within group
        ushort4 av = ((const ushort4*)(ab + (size_t)r.x * 64))[sub];
        float4 bv = ((const float4*)(bb + (size_t)r.y * 64))[sub];
        float t = fmaxf(bf2f(av.x) + bv.x, 0.f) * gv.x
                + fmaxf(bf2f(av.y) + bv.y, 0.f) * gv.y
                + fmaxf(bf2f(av.z) + bv.z, 0.f) * gv.z
                + fmaxf(bf2f(av.w) + bv.w, 0.f) * gv.w;
        #pragma unroll
        for (int o = 8; o > 0; o >>= 1) t += __shfl_xor(t, o, 64);
        float w = __int_as_float(r.z) / (1.f + __expf(-(t + gb)));
        if (sub == 0) sw[e] = make_int2(r.x, __float_as_int(w));
    }
}

// wave-per-node: gather+fma aggregation over bf16 h rows (no cross-lane in
// loop), then fused update MLP + LayerNorm in fp32. Writes h_out + hb_out.
__global__ __launch_bounds__(256) void agg_update_kernel(
    const int* __restrict__ row_ptr, const int2* __restrict__ sw,
    const ushort_t* __restrict__ hb_in, const float* __restrict__ h_in,
    const float* __restrict__ w1, const float* __restrict__ b1,
    const float* __restrict__ w2, const float* __restrict__ b2,
    const float* __restrict__ lng, const float* __restrict__ lnb,
    float* __restrict__ h_out, ushort_t* __restrict__ hb_out, int N) {
    __shared__ float ws1[64 * 64], ws2[64 * 64];  // 16 + 16 KB
    for (int i = threadIdx.x; i < 4096; i += blockDim.x) {
        ws1[i] = w1[i];
        ws2[i] = w2[i];
    }
    __syncthreads();
    const int lane = threadIdx.x & 63;
    const int wid  = blockIdx.x * (blockDim.x >> 6) + (threadIdx.x >> 6);
    const int nw   = gridDim.x * (blockDim.x >> 6);
    const float b1l = b1[lane], b2l = b2[lane];
    const float gl = lng[lane], bl = lnb[lane];
    for (int n = wid; n < N; n += nw) {
        const int beg = row_ptr[n], end = row_ptr[n + 1];
        float macc = 0.f, dacc = 0.f;
        int i = beg;
        for (; i + 4 <= end; i += 4) {
            int2 r0 = sw[i], r1 = sw[i + 1], r2 = sw[i + 2], r3 = sw[i + 3];
            float hv0 = bf2f(hb_in[(size_t)r0.x * 64 + lane]);
            float hv1 = bf2f(hb_in[(size_t)r1.x * 64 + lane]);
            float hv2 = bf2f(hb_in[(size_t)r2.x * 64 + lane]);
            float hv3 = bf2f(hb_in[(size_t)r3.x * 64 + lane]);
            float w0 = __int_as_float(r0.y), w1v = __int_as_float(r1.y);
            float w2v = __int_as_float(r2.y), w3v = __int_as_float(r3.y);
            macc = fmaf(w0, hv0, macc);
            macc = fmaf(w1v, hv1, macc);
            macc = fmaf(w2v, hv2, macc);
            macc = fmaf(w3v, hv3, macc);
            dacc += (w0 + w1v) + (w2v + w3v);
        }
        for (; i < end; ++i) {
            int2 r0 = sw[i];
            float hv0 = bf2f(hb_in[(size_t)r0.x * 64 + lane]);
            float w0 = __int_as_float(r0.y);
            macc = fmaf(w0, hv0, macc);
            dacc += w0;
        }
        // ---- fused update MLP + LayerNorm ----
        float neigh = macc / (dacc + 1e-8f);
        float acc = 0.f;
        #pragma unroll
        for (int k = 0; k < 64; ++k) {
            float tv = __shfl(neigh, k, 64);
            acc = fmaf(ws1[k * 64 + lane], tv, acc);
        }
        float t = fmaxf(acc + b1l, 0.f);
        float acc2 = 0.f;
        #pragma unroll
        for (int k = 0; k < 64; ++k) {
            float tv = __shfl(t, k, 64);
            acc2 = fmaf(ws2[k * 64 + lane], tv, acc2);
        }
        float pre = h_in[(size_t)n * 64 + lane] + acc2 + b2l;
        float s1 = wave_sum64(pre);
        float s2 = wave_sum64(pre * pre);
        float mean = s1 * (1.0f / 64.0f);
        float var  = s2 * (1.0f / 64.0f) - mean * mean;
        float hn = (pre - mean) * rsqrtf(var + 1e-5f) * gl + bl;
        h_out[(size_t)n * 64 + lane] = hn;
        hb_out[(size_t)n * 64 + lane] = f2bf(hn);
    }
}

// U = softplus(h @ toU_w + toU_b), K=32
__global__ __launch_bounds__(256) void out_kernel(
    const float* __restrict__ h, const float* __restrict__ tw,
    const float* __restrict__ tb, float* __restrict__ U, int N) {
    int gid = blockIdx.x * blockDim.x + threadIdx.x;
    int n = gid >> 5;
    int k = gid & 31;
    if (n >= N) return;
    float acc = tb[k];
    const float* hr = h + (size_t)n * 64;
    #pragma unroll 8
    for (int j = 0; j < 64; ++j) acc = fmaf(hr[j], tw[j * 32 + k], acc);
    float sp = acc > 0.f ? acc + log1pf(__expf(-acc)) : log1pf(__expf(acc));
    U[(size_t)n * 32 + k] = sp;
}

extern "C" void kernel_launch(void* const* d_in, const int* in_sizes, int n_in,
                              void* d_out, int out_size, void* d_ws, size_t ws_size,
                              hipStream_t stream) {
    const float* x       = (const float*)d_in[0];
    const int*   src     = (const int*)d_in[1];
    const int*   dst     = (const int*)d_in[2];
    const float* base_w  = (const float*)d_in[3];
    const float* enc_w1  = (const float*)d_in[4];
    const float* enc_b1  = (const float*)d_in[5];
    const float* enc_w2  = (const float*)d_in[6];
    const float* enc_b2  = (const float*)d_in[7];
    const float* gate_w1 = (const float*)d_in[8];
    const float* gate_b1 = (const float*)d_in[9];
    const float* gate_w2 = (const float*)d_in[10];
    const float* gate_b2 = (const float*)d_in[11];
    const float* upd_w1  = (const float*)d_in[12];
    const float* upd_b1  = (const float*)d_in[13];
    const float* upd_w2  = (const float*)d_in[14];
    const float* upd_b2  = (const float*)d_in[15];
    const float* ln_g    = (const float*)d_in[16];
    const float* ln_b    = (const float*)d_in[17];
    const float* rho_raw = (const float*)d_in[18];
    const float* toU_w   = (const float*)d_in[19];
    const float* toU_b   = (const float*)d_in[20];

    const int N = in_sizes[18];          // 50000
    const int C = in_sizes[0] / N;       // 256
    const int E = in_sizes[1];           // 800000
    const int L = 2;

    // workspace layout (float units), sections padded to 16B alignment
    float* ws  = (float*)d_ws;
    size_t off = 0;
    float* h0  = ws + off; off += (size_t)N * 64;
    float* h1  = ws + off; off += (size_t)N * 64;
    ushort_t* hb0 = (ushort_t*)(ws + off); off += (size_t)N * 32;
    ushort_t* hb1 = (ushort_t*)(ws + off); off += (size_t)N * 32;
    ushort_t* ab  = (ushort_t*)(ws + off); off += (size_t)N * 32;
    float* bb  = ws + off; off += (size_t)N * 64;
    int* row_ptr = (int*)(ws + off); off += (size_t)((N + 1 + 3) & ~3);
    int* cnt     = (int*)(ws + off); off += (size_t)((N + 3) & ~3);
    int4* recs   = (int4*)(ws + off); off += (size_t)E * 4;   // (s,d,c,0)
    int2* sw     = (int2*)(ws + off); off += (size_t)E * 2;   // (s,w)

    enc_kernel<<<512, 256, 0, stream>>>(x, enc_w1, enc_b1, enc_w2, enc_b2,
                                        h0, hb0, N, C);

    // CSR build (dst-sorted edge records); rho folded into scatter
    hipMemsetAsync(cnt, 0, (size_t)N * sizeof(int), stream);
    hist_kernel<<<(E + 255) / 256, 256, 0, stream>>>(dst, cnt, E);
    scan_kernel<<<1, 1024, 0, stream>>>(cnt, row_ptr, N);
    hipMemsetAsync(cnt, 0, (size_t)N * sizeof(int), stream);
    scatter_kernel<<<(E + 255) / 256, 256, 0, stream>>>(src, dst, base_w, rho_raw,
                                                        row_ptr, cnt, recs, E);

    float* h_cur = h0;  ushort_t* hb_cur = hb0;
    float* h_nxt = h1;  ushort_t* hb_nxt = hb1;
    for (int l = 0; l < L; ++l) {
        gateproj_kernel<<<1024, 256, 0, stream>>>(h_cur, gate_w1, gate_b1, ab, bb, N);
        gate_kernel<<<4096, 256, 0, stream>>>(recs, ab, bb, gate_w2, gate_b2, sw, E);
        agg_update_kernel<<<2048, 256, 0, stream>>>(
            row_ptr, sw, hb_cur, h_cur,
            upd_w1 + (size_t)l * 4096, upd_b1 + l * 64,
            upd_w2 + (size_t)l * 4096, upd_b2 + l * 64,
            ln_g + l * 64, ln_b + l * 64, h_nxt, hb_nxt, N);
        float* tf = h_cur; h_cur = h_nxt; h_nxt = tf;
        ushort_t* tb2 = hb_cur; hb_cur = hb_nxt; hb_nxt = tb2;
    }

    out_kernel<<<((N * 32) + 255) / 256, 256, 0, stream>>>(h_cur, toU_w, toU_b,
                                                           (float*)d_out, N);
}